// Round 10
// baseline (139.012 us; speedup 1.0000x reference)
//
#include <hip/hip_runtime.h>

// VQ via MFMA: x (32,64,64,64) fp32 NCHW, embed (512,64) fp32.
// Approx dists via bf16 MFMA (A = x-hi only; B = e-hi + e-lo -> 4 MFMAs,
// fp32 acc; missing term sum(x_lo*e) max ~0.03 << EPS) used for PRUNING;
// candidates within EPS of the wave-local row-min are re-checked in exact
// fp32 (same fmaf order as the R1-passing scalar kernel) -> argmin == np.
//
// R10 = R9 (68us, clean: no spill, WRITE 33MB) minus its 3 named stalls:
//  - Xs32 stride 68 -> 69 words (odd): staging writes were 8-way bank
//    conflicts (836K SQ_LDS_BANK_CONFLICT); odd stride = 32-bank cycle,
//    conflict-free. Recheck/A-build read Xs32 scalar (no 16B align needed).
//  - min-update 6 -> 4 VALU/elem: v_and_or pack + v_med3 for min2
//    (m2' = med3(kf, m1, m2) = second-smallest, given invariant m1 <= m2).
//  - XsH dropped from LDS (A-frags built per-wave from Xs32 + f2bf, one-time
//    ~300cyc): LDS 31.7 -> 22.3KB -> 7 blocks/CU.
//  - first two B-tile prefetches hoisted above barrier 1 (independent of
//    staging; L2 latency overlaps the barrier wait).
// Spill tripwire: WRITE_SIZE must stay ~33MB, VGPR <= ~80.

#define VQ_N 131072
#define VQ_D 64
#define VQ_K 512
#define VQ_HW 4096
#define ROWS 64          // rows per block
#define EPS 0.25f        // prune margin; approx err max ~0.03, key quantum 0.016
#define QW 512           // queue entries per wave
#define X32_STR 69       // floats/row: ODD -> conflict-free staging writes

typedef __attribute__((ext_vector_type(8))) short short8;
typedef __attribute__((ext_vector_type(4))) float f32x4;

static __device__ __forceinline__ unsigned short f2bf(float f) {
    unsigned u = __float_as_uint(f);
    unsigned r = (u + 0x7fffu + ((u >> 16) & 1u)) >> 16;   // round-nearest-even
    return (unsigned short)r;
}
static __device__ __forceinline__ float bf2f(unsigned short h) {
    return __uint_as_float(((unsigned)h) << 16);
}
// order-preserving float->uint for the exact-recheck u64 key
static __device__ __forceinline__ unsigned fenc(float f) {
    unsigned u = __float_as_uint(f);
    return u ^ ((unsigned)(((int)u) >> 31) | 0x80000000u);
}
// clear low 9 mantissa bits (decode of embedded-index float keys)
static __device__ __forceinline__ float clr9(float f) {
    return __uint_as_float(__float_as_uint(f) & 0xFFFFFE00u);
}

// prep: embed fp32 -> bf16 hi/lo (EH, EL); first 512 threads also do e_sq
__global__ __launch_bounds__(256) void vq_prep_kernel(
    const float* __restrict__ embed,
    unsigned short* __restrict__ EH, unsigned short* __restrict__ EL,
    float* __restrict__ esq) {
    int g = blockIdx.x * 256 + threadIdx.x;   // 32768 elems
    float f = embed[g];
    unsigned short h = f2bf(f);
    EH[g] = h;
    EL[g] = f2bf(f - bf2f(h));
    if (g < VQ_K) {
        const float* e = embed + g * VQ_D;
        float p0 = 0.f, p1 = 0.f, p2 = 0.f, p3 = 0.f;
#pragma unroll
        for (int d = 0; d < VQ_D; d += 4) {
            p0 = fmaf(e[d + 0], e[d + 0], p0);
            p1 = fmaf(e[d + 1], e[d + 1], p1);
            p2 = fmaf(e[d + 2], e[d + 2], p2);
            p3 = fmaf(e[d + 3], e[d + 3], p3);
        }
        esq[g] = (p0 + p1) + (p2 + p3);
    }
}

// load B fragments + esq for local code-tile nt into NAMED regs (no arrays)
#define LOADB(nt, BH0, BH1, BL0, BL1, ES) {                        \
    int _eo = (nb + ((nt) << 4) + lrow) * VQ_D + (quad << 3);      \
    BH0 = *(const short8*)&EH[_eo];                                \
    BH1 = *(const short8*)&EH[_eo + 32];                           \
    BL0 = *(const short8*)&EL[_eo];                                \
    BL1 = *(const short8*)&EL[_eo + 32];                           \
    ES  = esq[nb + ((nt) << 4) + lrow]; }

// 4-MFMA dist (A-hi x B-hi + A-hi x B-lo) for row-tile rt + 4-VALU key update
#define PROCESS1(nt, rt, BH0, BH1, BL0, BL1, ES) {                             \
    f32x4 acc = {0.f, 0.f, 0.f, 0.f};                                          \
    acc = __builtin_amdgcn_mfma_f32_16x16x32_bf16(AH##rt##0, BH0, acc, 0, 0, 0); \
    acc = __builtin_amdgcn_mfma_f32_16x16x32_bf16(AH##rt##1, BH1, acc, 0, 0, 0); \
    acc = __builtin_amdgcn_mfma_f32_16x16x32_bf16(AH##rt##0, BL0, acc, 0, 0, 0); \
    acc = __builtin_amdgcn_mfma_f32_16x16x32_bf16(AH##rt##1, BL1, acc, 0, 0, 0); \
    unsigned _nn = (unsigned)(nb + ((nt) << 4) + lrow);  /* global code id */  \
    _Pragma("unroll")                                                          \
    for (int i = 0; i < 4; ++i) {      /* C: col(n)=lane&15, row=quad*4+i */   \
        float v = fmaf(-2.f, acc[i], ES);                                      \
        float kf = __uint_as_float((__float_as_uint(v) & 0xFFFFFE00u) | _nn);  \
        m2[rt][i] = __builtin_amdgcn_fmed3f(kf, m1[rt][i], m2[rt][i]);         \
        m1[rt][i] = fminf(m1[rt][i], kf);                                      \
    } }

#define PROCESS4(nt, BH0, BH1, BL0, BL1, ES)     \
    PROCESS1(nt, 0, BH0, BH1, BL0, BL1, ES)      \
    PROCESS1(nt, 1, BH0, BH1, BL0, BL1, ES)      \
    PROCESS1(nt, 2, BH0, BH1, BL0, BL1, ES)      \
    PROCESS1(nt, 3, BH0, BH1, BL0, BL1, ES)

__global__ __launch_bounds__(256, 2) void vq_mfma_kernel(
    const float* __restrict__ x, const float* __restrict__ embed,
    const float* __restrict__ esq,
    const unsigned short* __restrict__ EH, const unsigned short* __restrict__ EL,
    float* __restrict__ out_q, float* __restrict__ out_idx) {
    __shared__ float Xs32[ROWS * X32_STR];                       // 17664 B
    __shared__ unsigned long long row_best[ROWS];                // 512 B
    __shared__ int qcnt[4];
    __shared__ unsigned short qbuf[4 * QW];                      // 4096 B

    const int t   = threadIdx.x;
    const int n0  = blockIdx.x * ROWS;
    const int b   = n0 >> 12;        // 64 | 4096 -> block stays in one image
    const int hw0 = n0 & 4095;

    const int lane = t & 63;
    const int wave = t >> 6;
    const int lrow = lane & 15;
    const int quad = lane >> 4;
    const int nb   = wave * 128;     // this wave's 128 codes

    if (t < ROWS) row_best[t] = ~0ull;
    if (t < 4) qcnt[t] = 0;

    // ---- prefetch first two B tiles BEFORE the barrier (independent) ----
    short8 bh0a, bh1a, bl0a, bl1a; float esa;
    short8 bh0b, bh1b, bl0b, bl1b; float esb;
    LOADB(0, bh0a, bh1a, bl0a, bl1a, esa)
    LOADB(1, bh0b, bh1b, bl0b, bl1b, esb)

    // ---- stage X (fp32 only); global loads coalesced over hw;
    //      odd stride -> conflict-free LDS writes ----
    {
        const int hw = t & 63;
        const int d0 = (t >> 6) * 16;
        const float* xb = x + (size_t)b * (VQ_D * VQ_HW) + hw0 + hw;
#pragma unroll
        for (int dd = 0; dd < 16; ++dd)
            Xs32[hw * X32_STR + d0 + dd] = xb[(d0 + dd) * VQ_HW];
    }
    __syncthreads();   // barrier 1

    // ---- A fragments (hi only) built from Xs32, named regs ----
    short8 AH00, AH01, AH10, AH11, AH20, AH21, AH30, AH31;
#define BUILDA(rt) {                                                           \
    const float* _xr = &Xs32[((rt) * 16 + lrow) * X32_STR + (quad << 3)];      \
    _Pragma("unroll")                                                          \
    for (int j = 0; j < 8; ++j) {                                              \
        AH##rt##0[j] = (short)f2bf(_xr[j]);                                    \
        AH##rt##1[j] = (short)f2bf(_xr[32 + j]);                               \
    } }
    BUILDA(0) BUILDA(1) BUILDA(2) BUILDA(3)
#undef BUILDA

    float m1[4][4], m2[4][4];
#pragma unroll
    for (int rt = 0; rt < 4; ++rt)
#pragma unroll
        for (int i = 0; i < 4; ++i) {
            m1[rt][i] = __uint_as_float(0x7F800000u);   // +inf (low 9 bits 0)
            m2[rt][i] = __uint_as_float(0x7F800000u);
        }

    // ---- main loop: 8 code-tiles, double-buffered NAMED-reg prefetch ----
#pragma unroll 1
    for (int nt = 0; nt < 8; nt += 2) {
        PROCESS4(nt, bh0a, bh1a, bl0a, bl1a, esa)
        int ntp = (nt + 2 < 8) ? nt + 2 : 7;    // clamped harmless reload
        LOADB(ntp, bh0a, bh1a, bl0a, bl1a, esa)
        PROCESS4(nt + 1, bh0b, bh1b, bl0b, bl1b, esb)
        int ntq = (nt + 3 < 8) ? nt + 3 : 7;
        LOADB(ntq, bh0b, bh1b, bl0b, bl1b, esb)
    }

    // ---- wave-local row-min over the 16 n-lanes (per rt,i) ----
    float g1[4][4];
#pragma unroll
    for (int rt = 0; rt < 4; ++rt)
#pragma unroll
        for (int i = 0; i < 4; ++i) g1[rt][i] = m1[rt][i];
#pragma unroll
    for (int s = 1; s <= 8; s <<= 1)
#pragma unroll
        for (int rt = 0; rt < 4; ++rt)
#pragma unroll
            for (int i = 0; i < 4; ++i)
                g1[rt][i] = fminf(g1[rt][i], __shfl_xor(g1[rt][i], s));

    // ---- push candidates (within EPS of wave-local row-min) ----
#pragma unroll
    for (int rt = 0; rt < 4; ++rt)
#pragma unroll
        for (int i = 0; i < 4; ++i) {
            int m = rt * 16 + quad * 4 + i;            // block-local row 0..63
            float thr = clr9(g1[rt][i]) + EPS;
            if (clr9(m1[rt][i]) <= thr) {
                int id = atomicAdd(&qcnt[wave], 1);
                if (id < QW)
                    qbuf[wave * QW + id] = (unsigned short)
                        (((unsigned)m << 9) | (__float_as_uint(m1[rt][i]) & 511u));
            }
            if (clr9(m2[rt][i]) <= thr) {
                int id = atomicAdd(&qcnt[wave], 1);
                if (id < QW)
                    qbuf[wave * QW + id] = (unsigned short)
                        (((unsigned)m << 9) | (__float_as_uint(m2[rt][i]) & 511u));
            }
        }
    asm volatile("s_waitcnt lgkmcnt(0)");   // wave-local queue visible

    // ---- exact fp32 recheck (same fmaf order as R1 kernel), wave-local ----
    int qc = atomicAdd(&qcnt[wave], 0);
    if (qc > QW) qc = QW;
    for (int qi = lane; qi < qc; qi += 64) {
        unsigned e = qbuf[wave * QW + qi];
        int m = (int)(e >> 9), n = (int)(e & 511u);
        const float4* er = (const float4*)(embed + n * VQ_D);
        const float* xr = &Xs32[m * X32_STR];
        float dot = 0.f;
#pragma unroll
        for (int d4 = 0; d4 < 16; ++d4) {
            float4 ev = er[d4];
            dot = fmaf(xr[4 * d4 + 0], ev.x, dot);
            dot = fmaf(xr[4 * d4 + 1], ev.y, dot);
            dot = fmaf(xr[4 * d4 + 2], ev.z, dot);
            dot = fmaf(xr[4 * d4 + 3], ev.w, dot);
        }
        float v = fmaf(-2.f, dot, esq[n]);
        unsigned long long key =
            (((unsigned long long)fenc(v)) << 32) | (unsigned)n;
        atomicMin(&row_best[m], key);   // exact order; equal dist -> smaller n
    }
    __syncthreads();   // barrier 2: all waves' rechecks done

    // ---- outputs: indices + fully-coalesced quantized rows ----
    if (t < ROWS) out_idx[n0 + t] = (float)(unsigned)(row_best[t] & 0xffffffffu);

#pragma unroll
    for (int it = 0; it < 4; ++it) {
        int o   = it * 1024 + t * 4;          // 64 rows x 64 floats, contiguous
        int row = o >> 6;
        int col = o & 63;
        unsigned k = (unsigned)(row_best[row] & 0xffffffffu);
        float4 val = *(const float4*)(embed + k * VQ_D + col);
        *(float4*)(out_q + (size_t)n0 * VQ_D + o) = val;
    }
}

extern "C" void kernel_launch(void* const* d_in, const int* in_sizes, int n_in,
                              void* d_out, int out_size, void* d_ws, size_t ws_size,
                              hipStream_t stream) {
    const float* x     = (const float*)d_in[0];
    const float* embed = (const float*)d_in[1];
    float* out_q   = (float*)d_out;
    float* out_idx = (float*)d_out + (size_t)VQ_N * VQ_D;

    float* esq          = (float*)d_ws;                          // 512 f
    unsigned short* EH  = (unsigned short*)((char*)d_ws + 2048);
    unsigned short* EL  = (unsigned short*)((char*)d_ws + 2048 + VQ_K * VQ_D * 2);

    vq_prep_kernel<<<(VQ_K * VQ_D) / 256, 256, 0, stream>>>(embed, EH, EL, esq);
    vq_mfma_kernel<<<VQ_N / ROWS, 256, 0, stream>>>(x, embed, esq, EH, EL, out_q, out_idx);
}

// Round 11
// 138.140 us; speedup vs baseline: 1.0063x; 1.0063x over previous
//
#include <hip/hip_runtime.h>

// VQ via MFMA: x (32,64,64,64) fp32 NCHW, embed (512,64) fp32.
// Approx dists via bf16 MFMA (A = x-hi only; B = e-hi + e-lo -> 4 MFMAs,
// fp32 acc; missing term sum(x_lo*e) max ~0.03 << EPS) used for PRUNING;
// candidates within EPS of the wave-local row-min are re-checked in exact
// fp32 (same fmaf order as the R1-passing scalar kernel) -> argmin == np.
//
// R11 = R9 (68us best) + verified-sound R10 deltas only:
//  - KEEP XsH in LDS (R10 dropped it -> 64 scalar ds_read + 128 f2bf per
//    thread redundant per wave; conflicts 836K->1.35M, dur 68->79. Reverted.)
//  - Xs32 stride 68 -> 69 (odd): staging-write bank = (5*hw+d)%32, 2-way=free
//    (68 was 8-way). Recheck reads Xs32 scalar.
//  - med3 min-update (4 VALU/elem) + pre-barrier B prefetch.
//  - NEW: atomic-free candidate push. Row keys are UNIQUE (index in low 9
//    bits), so exactly one lane has m1==g1 (the row winner): it writes slot m
//    directly. Only near-tie extras (typ 0-2/wave) use atomicAdd. Removes
//    ~64 serialized same-address LDS atomics per wave; recheck = fixed 64+.
// Spill tripwire: WRITE_SIZE must stay ~33MB, VGPR <= ~80.

#define VQ_N 131072
#define VQ_D 64
#define VQ_K 512
#define VQ_HW 4096
#define ROWS 64          // rows per block
#define EPS 0.25f        // prune margin; approx err max ~0.03, key quantum 0.016
#define QW 512           // queue entries per wave (slots 0..63 = row winners)
#define XH_STR 72        // shorts/row (64+8 pad), 144B stride (16B-aligned)
#define X32_STR 69       // floats/row: ODD -> conflict-free staging writes

typedef __attribute__((ext_vector_type(8))) short short8;
typedef __attribute__((ext_vector_type(4))) float f32x4;

static __device__ __forceinline__ unsigned short f2bf(float f) {
    unsigned u = __float_as_uint(f);
    unsigned r = (u + 0x7fffu + ((u >> 16) & 1u)) >> 16;   // round-nearest-even
    return (unsigned short)r;
}
static __device__ __forceinline__ float bf2f(unsigned short h) {
    return __uint_as_float(((unsigned)h) << 16);
}
// order-preserving float->uint for the exact-recheck u64 key
static __device__ __forceinline__ unsigned fenc(float f) {
    unsigned u = __float_as_uint(f);
    return u ^ ((unsigned)(((int)u) >> 31) | 0x80000000u);
}
// clear low 9 mantissa bits (decode of embedded-index float keys)
static __device__ __forceinline__ float clr9(float f) {
    return __uint_as_float(__float_as_uint(f) & 0xFFFFFE00u);
}

// prep: embed fp32 -> bf16 hi/lo (EH, EL); first 512 threads also do e_sq
__global__ __launch_bounds__(256) void vq_prep_kernel(
    const float* __restrict__ embed,
    unsigned short* __restrict__ EH, unsigned short* __restrict__ EL,
    float* __restrict__ esq) {
    int g = blockIdx.x * 256 + threadIdx.x;   // 32768 elems
    float f = embed[g];
    unsigned short h = f2bf(f);
    EH[g] = h;
    EL[g] = f2bf(f - bf2f(h));
    if (g < VQ_K) {
        const float* e = embed + g * VQ_D;
        float p0 = 0.f, p1 = 0.f, p2 = 0.f, p3 = 0.f;
#pragma unroll
        for (int d = 0; d < VQ_D; d += 4) {
            p0 = fmaf(e[d + 0], e[d + 0], p0);
            p1 = fmaf(e[d + 1], e[d + 1], p1);
            p2 = fmaf(e[d + 2], e[d + 2], p2);
            p3 = fmaf(e[d + 3], e[d + 3], p3);
        }
        esq[g] = (p0 + p1) + (p2 + p3);
    }
}

// load B fragments + esq for local code-tile nt into NAMED regs (no arrays)
#define LOADB(nt, BH0, BH1, BL0, BL1, ES) {                        \
    int _eo = (nb + ((nt) << 4) + lrow) * VQ_D + (quad << 3);      \
    BH0 = *(const short8*)&EH[_eo];                                \
    BH1 = *(const short8*)&EH[_eo + 32];                           \
    BL0 = *(const short8*)&EL[_eo];                                \
    BL1 = *(const short8*)&EL[_eo + 32];                           \
    ES  = esq[nb + ((nt) << 4) + lrow]; }

// 4-MFMA dist (A-hi x B-hi + A-hi x B-lo) for row-tile rt + 4-VALU key update
#define PROCESS1(nt, rt, BH0, BH1, BL0, BL1, ES) {                             \
    f32x4 acc = {0.f, 0.f, 0.f, 0.f};                                          \
    acc = __builtin_amdgcn_mfma_f32_16x16x32_bf16(AH##rt##0, BH0, acc, 0, 0, 0); \
    acc = __builtin_amdgcn_mfma_f32_16x16x32_bf16(AH##rt##1, BH1, acc, 0, 0, 0); \
    acc = __builtin_amdgcn_mfma_f32_16x16x32_bf16(AH##rt##0, BL0, acc, 0, 0, 0); \
    acc = __builtin_amdgcn_mfma_f32_16x16x32_bf16(AH##rt##1, BL1, acc, 0, 0, 0); \
    unsigned _nn = (unsigned)(nb + ((nt) << 4) + lrow);  /* global code id */  \
    _Pragma("unroll")                                                          \
    for (int i = 0; i < 4; ++i) {      /* C: col(n)=lane&15, row=quad*4+i */   \
        float v = fmaf(-2.f, acc[i], ES);                                      \
        float kf = __uint_as_float((__float_as_uint(v) & 0xFFFFFE00u) | _nn);  \
        m2[rt][i] = __builtin_amdgcn_fmed3f(kf, m1[rt][i], m2[rt][i]);         \
        m1[rt][i] = fminf(m1[rt][i], kf);                                      \
    } }

#define PROCESS4(nt, BH0, BH1, BL0, BL1, ES)     \
    PROCESS1(nt, 0, BH0, BH1, BL0, BL1, ES)      \
    PROCESS1(nt, 1, BH0, BH1, BL0, BL1, ES)      \
    PROCESS1(nt, 2, BH0, BH1, BL0, BL1, ES)      \
    PROCESS1(nt, 3, BH0, BH1, BL0, BL1, ES)

__global__ __launch_bounds__(256, 2) void vq_mfma_kernel(
    const float* __restrict__ x, const float* __restrict__ embed,
    const float* __restrict__ esq,
    const unsigned short* __restrict__ EH, const unsigned short* __restrict__ EL,
    float* __restrict__ out_q, float* __restrict__ out_idx) {
    __shared__ __align__(16) unsigned short XsH[ROWS * XH_STR];  // 9216 B
    __shared__ float Xs32[ROWS * X32_STR];                       // 17664 B
    __shared__ unsigned long long row_best[ROWS];                // 512 B
    __shared__ int qcnt[4];
    __shared__ unsigned short qbuf[4 * QW];                      // 4096 B

    const int t   = threadIdx.x;
    const int n0  = blockIdx.x * ROWS;
    const int b   = n0 >> 12;        // 64 | 4096 -> block stays in one image
    const int hw0 = n0 & 4095;

    const int lane = t & 63;
    const int wave = t >> 6;
    const int lrow = lane & 15;
    const int quad = lane >> 4;
    const int nb   = wave * 128;     // this wave's 128 codes

    if (t < ROWS) row_best[t] = ~0ull;
    if (t < 4) qcnt[t] = ROWS;       // slots 0..63 reserved for row winners

    // ---- prefetch first two B tiles BEFORE the barrier (independent) ----
    short8 bh0a, bh1a, bl0a, bl1a; float esa;
    short8 bh0b, bh1b, bl0b, bl1b; float esb;
    LOADB(0, bh0a, bh1a, bl0a, bl1a, esa)
    LOADB(1, bh0b, bh1b, bl0b, bl1b, esb)

    // ---- stage X: fp32 (odd stride, conflict-free) + bf16-hi (b128) ----
    {
        const int hw = t & 63;
        const int d0 = (t >> 6) * 16;
        const float* xb = x + (size_t)b * (VQ_D * VQ_HW) + hw0 + hw;
        short8 H0, H1;
#pragma unroll
        for (int dd = 0; dd < 8; ++dd) {
            float f = xb[(d0 + dd) * VQ_HW];
            Xs32[hw * X32_STR + d0 + dd] = f;
            H0[dd] = (short)f2bf(f);
        }
#pragma unroll
        for (int dd = 0; dd < 8; ++dd) {
            float f = xb[(d0 + 8 + dd) * VQ_HW];
            Xs32[hw * X32_STR + d0 + 8 + dd] = f;
            H1[dd] = (short)f2bf(f);
        }
        *(short8*)&XsH[hw * XH_STR + d0]     = H0;
        *(short8*)&XsH[hw * XH_STR + d0 + 8] = H1;
    }
    __syncthreads();   // barrier 1

    // ---- A fragments (hi only) via ds_read_b128, named regs ----
    short8 AH00, AH01, AH10, AH11, AH20, AH21, AH30, AH31;
#define LOADA(rt)                                                              \
    AH##rt##0 = *(const short8*)&XsH[(rt * 16 + lrow) * XH_STR + quad * 8];    \
    AH##rt##1 = *(const short8*)&XsH[(rt * 16 + lrow) * XH_STR + 32 + quad * 8];
    LOADA(0) LOADA(1) LOADA(2) LOADA(3)
#undef LOADA

    float m1[4][4], m2[4][4];
#pragma unroll
    for (int rt = 0; rt < 4; ++rt)
#pragma unroll
        for (int i = 0; i < 4; ++i) {
            m1[rt][i] = __uint_as_float(0x7F800000u);   // +inf (low 9 bits 0)
            m2[rt][i] = __uint_as_float(0x7F800000u);
        }

    // ---- main loop: 8 code-tiles, double-buffered NAMED-reg prefetch ----
#pragma unroll 1
    for (int nt = 0; nt < 8; nt += 2) {
        PROCESS4(nt, bh0a, bh1a, bl0a, bl1a, esa)
        int ntp = (nt + 2 < 8) ? nt + 2 : 7;    // clamped harmless reload
        LOADB(ntp, bh0a, bh1a, bl0a, bl1a, esa)
        PROCESS4(nt + 1, bh0b, bh1b, bl0b, bl1b, esb)
        int ntq = (nt + 3 < 8) ? nt + 3 : 7;
        LOADB(ntq, bh0b, bh1b, bl0b, bl1b, esb)
    }

    // ---- wave-local row-min over the 16 n-lanes (per rt,i) ----
    float g1[4][4];
#pragma unroll
    for (int rt = 0; rt < 4; ++rt)
#pragma unroll
        for (int i = 0; i < 4; ++i) g1[rt][i] = m1[rt][i];
#pragma unroll
    for (int s = 1; s <= 8; s <<= 1)
#pragma unroll
        for (int rt = 0; rt < 4; ++rt)
#pragma unroll
            for (int i = 0; i < 4; ++i)
                g1[rt][i] = fminf(g1[rt][i], __shfl_xor(g1[rt][i], s));

    // ---- push candidates: winner -> fixed slot m (keys unique, exactly one
    //      lane matches g1); near-tie extras -> atomic slots 64+ ----
#pragma unroll
    for (int rt = 0; rt < 4; ++rt)
#pragma unroll
        for (int i = 0; i < 4; ++i) {
            int m = rt * 16 + quad * 4 + i;            // block-local row 0..63
            float thr = clr9(g1[rt][i]) + EPS;
            if (m1[rt][i] == g1[rt][i]) {
                qbuf[wave * QW + m] = (unsigned short)
                    (((unsigned)m << 9) | (__float_as_uint(m1[rt][i]) & 511u));
            } else if (clr9(m1[rt][i]) <= thr) {
                int id = atomicAdd(&qcnt[wave], 1);
                if (id < QW)
                    qbuf[wave * QW + id] = (unsigned short)
                        (((unsigned)m << 9) | (__float_as_uint(m1[rt][i]) & 511u));
            }
            if (clr9(m2[rt][i]) <= thr) {
                int id = atomicAdd(&qcnt[wave], 1);
                if (id < QW)
                    qbuf[wave * QW + id] = (unsigned short)
                        (((unsigned)m << 9) | (__float_as_uint(m2[rt][i]) & 511u));
            }
        }
    asm volatile("s_waitcnt lgkmcnt(0)");   // wave-local queue visible

    // ---- exact fp32 recheck (same fmaf order as R1 kernel), wave-local ----
    int qc = atomicAdd(&qcnt[wave], 0);
    if (qc > QW) qc = QW;
    for (int qi = lane; qi < qc; qi += 64) {
        unsigned e = qbuf[wave * QW + qi];
        int m = (int)(e >> 9), n = (int)(e & 511u);
        const float4* er = (const float4*)(embed + n * VQ_D);
        const float* xr = &Xs32[m * X32_STR];
        float dot = 0.f;
#pragma unroll
        for (int d4 = 0; d4 < 16; ++d4) {
            float4 ev = er[d4];
            dot = fmaf(xr[4 * d4 + 0], ev.x, dot);
            dot = fmaf(xr[4 * d4 + 1], ev.y, dot);
            dot = fmaf(xr[4 * d4 + 2], ev.z, dot);
            dot = fmaf(xr[4 * d4 + 3], ev.w, dot);
        }
        float v = fmaf(-2.f, dot, esq[n]);
        unsigned long long key =
            (((unsigned long long)fenc(v)) << 32) | (unsigned)n;
        atomicMin(&row_best[m], key);   // exact order; equal dist -> smaller n
    }
    __syncthreads();   // barrier 2: all waves' rechecks done

    // ---- outputs: indices + fully-coalesced quantized rows ----
    if (t < ROWS) out_idx[n0 + t] = (float)(unsigned)(row_best[t] & 0xffffffffu);

#pragma unroll
    for (int it = 0; it < 4; ++it) {
        int o   = it * 1024 + t * 4;          // 64 rows x 64 floats, contiguous
        int row = o >> 6;
        int col = o & 63;
        unsigned k = (unsigned)(row_best[row] & 0xffffffffu);
        float4 val = *(const float4*)(embed + k * VQ_D + col);
        *(float4*)(out_q + (size_t)n0 * VQ_D + o) = val;
    }
}

extern "C" void kernel_launch(void* const* d_in, const int* in_sizes, int n_in,
                              void* d_out, int out_size, void* d_ws, size_t ws_size,
                              hipStream_t stream) {
    const float* x     = (const float*)d_in[0];
    const float* embed = (const float*)d_in[1];
    float* out_q   = (float*)d_out;
    float* out_idx = (float*)d_out + (size_t)VQ_N * VQ_D;

    float* esq          = (float*)d_ws;                          // 512 f
    unsigned short* EH  = (unsigned short*)((char*)d_ws + 2048);
    unsigned short* EL  = (unsigned short*)((char*)d_ws + 2048 + VQ_K * VQ_D * 2);

    vq_prep_kernel<<<(VQ_K * VQ_D) / 256, 256, 0, stream>>>(embed, EH, EL, esq);
    vq_mfma_kernel<<<VQ_N / ROWS, 256, 0, stream>>>(x, embed, esq, EH, EL, out_q, out_idx);
}

// Round 12
// 122.947 us; speedup vs baseline: 1.1307x; 1.1236x over previous
//
#include <hip/hip_runtime.h>

// VQ via MFMA: x (32,64,64,64) fp32 NCHW, embed (512,64) fp32.
// Approx dists via SINGLE-PASS fp16 MFMA (2 x mfma_f32_16x16x32_f16 per
// 16x16 tile, fp32 acc). Worst-case dist err <= 2*|x.e|*2^-10 ~ 0.18 << EPS
// 0.5; candidates within EPS of the wave-local row-min re-checked in exact
// fp32 (same fmaf order as the R1-passing scalar kernel) -> argmin == np.
//
// R12 = R11 (69us, absmax 0) with the bf16 hi/lo split replaced by fp16:
// R11 was 62% stall-bound (MfmaUtil 9 + VALUBusy 29) with the per-tile B
// round trips to L2 the prime suspect. fp16 halves B bytes (EL deleted),
// halves MFMA count/chain depth, cuts staging cvt 3->1 VALU, and the freed
// regs buy prefetch depth 4 (~600 issue-cyc cover >= 2-3x L2 latency).
// Spill tripwire: WRITE_SIZE must stay ~33MB, VGPR <= ~96.

#define VQ_N 131072
#define VQ_D 64
#define VQ_K 512
#define VQ_HW 4096
#define ROWS 64          // rows per block
#define EPS 0.5f         // prune margin; fp16 worst-case err ~0.18, typ ~0.01
#define QW 512           // queue entries per wave (slots 0..63 = row winners)
#define XH_STR 72        // f16/row (64+8 pad), 144B stride (16B-aligned)
#define X32_STR 69       // floats/row: ODD -> conflict-free staging writes

typedef __attribute__((ext_vector_type(8))) _Float16 half8;
typedef __attribute__((ext_vector_type(4))) float f32x4;

// order-preserving float->uint for the exact-recheck u64 key
static __device__ __forceinline__ unsigned fenc(float f) {
    unsigned u = __float_as_uint(f);
    return u ^ ((unsigned)(((int)u) >> 31) | 0x80000000u);
}
// clear low 9 mantissa bits (decode of embedded-index float keys)
static __device__ __forceinline__ float clr9(float f) {
    return __uint_as_float(__float_as_uint(f) & 0xFFFFFE00u);
}

// prep: embed fp32 -> fp16 (EH); first 512 threads also do e_sq
__global__ __launch_bounds__(256) void vq_prep_kernel(
    const float* __restrict__ embed,
    _Float16* __restrict__ EH, float* __restrict__ esq) {
    int g = blockIdx.x * 256 + threadIdx.x;   // 32768 elems
    EH[g] = (_Float16)embed[g];
    if (g < VQ_K) {
        const float* e = embed + g * VQ_D;
        float p0 = 0.f, p1 = 0.f, p2 = 0.f, p3 = 0.f;
#pragma unroll
        for (int d = 0; d < VQ_D; d += 4) {
            p0 = fmaf(e[d + 0], e[d + 0], p0);
            p1 = fmaf(e[d + 1], e[d + 1], p1);
            p2 = fmaf(e[d + 2], e[d + 2], p2);
            p3 = fmaf(e[d + 3], e[d + 3], p3);
        }
        esq[g] = (p0 + p1) + (p2 + p3);
    }
}

// load B fragment + esq for local code-tile nt into NAMED regs (no arrays)
#define LOADB(nt, F0, F1, ES) {                                    \
    int _eo = (nb + ((nt) << 4) + lrow) * VQ_D + (quad << 3);      \
    F0 = *(const half8*)&EH[_eo];                                  \
    F1 = *(const half8*)&EH[_eo + 32];                             \
    ES = esq[nb + ((nt) << 4) + lrow]; }

// 2-MFMA fp16 dist for row-tile rt + 4-VALU key update
#define PROCESS1(nt, rt, F0, F1, ES) {                                         \
    f32x4 acc = {0.f, 0.f, 0.f, 0.f};                                          \
    acc = __builtin_amdgcn_mfma_f32_16x16x32_f16(AH##rt##0, F0, acc, 0, 0, 0); \
    acc = __builtin_amdgcn_mfma_f32_16x16x32_f16(AH##rt##1, F1, acc, 0, 0, 0); \
    unsigned _nn = (unsigned)(nb + ((nt) << 4) + lrow);  /* global code id */  \
    _Pragma("unroll")                                                          \
    for (int i = 0; i < 4; ++i) {      /* C: col(n)=lane&15, row=quad*4+i */   \
        float v = fmaf(-2.f, acc[i], ES);                                      \
        float kf = __uint_as_float((__float_as_uint(v) & 0xFFFFFE00u) | _nn);  \
        m2[rt][i] = __builtin_amdgcn_fmed3f(kf, m1[rt][i], m2[rt][i]);         \
        m1[rt][i] = fminf(m1[rt][i], kf);                                      \
    } }

#define PROCESS4(nt, F0, F1, ES)     \
    PROCESS1(nt, 0, F0, F1, ES)      \
    PROCESS1(nt, 1, F0, F1, ES)      \
    PROCESS1(nt, 2, F0, F1, ES)      \
    PROCESS1(nt, 3, F0, F1, ES)

__global__ __launch_bounds__(256, 2) void vq_mfma_kernel(
    const float* __restrict__ x, const float* __restrict__ embed,
    const float* __restrict__ esq, const _Float16* __restrict__ EH,
    float* __restrict__ out_q, float* __restrict__ out_idx) {
    __shared__ __align__(16) _Float16 XsH[ROWS * XH_STR];        // 9216 B
    __shared__ float Xs32[ROWS * X32_STR];                       // 17664 B
    __shared__ unsigned long long row_best[ROWS];                // 512 B
    __shared__ int qcnt[4];
    __shared__ unsigned short qbuf[4 * QW];                      // 4096 B

    const int t   = threadIdx.x;
    const int n0  = blockIdx.x * ROWS;
    const int b   = n0 >> 12;        // 64 | 4096 -> block stays in one image
    const int hw0 = n0 & 4095;

    const int lane = t & 63;
    const int wave = t >> 6;
    const int lrow = lane & 15;
    const int quad = lane >> 4;
    const int nb   = wave * 128;     // this wave's 128 codes

    if (t < ROWS) row_best[t] = ~0ull;
    if (t < 4) qcnt[t] = ROWS;       // slots 0..63 reserved for row winners

    // ---- prefetch first four B tiles BEFORE the barrier (independent) ----
    half8 fa0, fa1, fb0, fb1, fc0, fc1, fd0, fd1;
    float esa, esb, esc, esd;
    LOADB(0, fa0, fa1, esa)
    LOADB(1, fb0, fb1, esb)
    LOADB(2, fc0, fc1, esc)
    LOADB(3, fd0, fd1, esd)

    // ---- stage X: fp32 (odd stride, conflict-free) + fp16 (b128) ----
    {
        const int hw = t & 63;
        const int d0 = (t >> 6) * 16;
        const float* xb = x + (size_t)b * (VQ_D * VQ_HW) + hw0 + hw;
        half8 H0, H1;
#pragma unroll
        for (int dd = 0; dd < 8; ++dd) {
            float f = xb[(d0 + dd) * VQ_HW];
            Xs32[hw * X32_STR + d0 + dd] = f;
            H0[dd] = (_Float16)f;
        }
#pragma unroll
        for (int dd = 0; dd < 8; ++dd) {
            float f = xb[(d0 + 8 + dd) * VQ_HW];
            Xs32[hw * X32_STR + d0 + 8 + dd] = f;
            H1[dd] = (_Float16)f;
        }
        *(half8*)&XsH[hw * XH_STR + d0]     = H0;
        *(half8*)&XsH[hw * XH_STR + d0 + 8] = H1;
    }
    __syncthreads();   // barrier 1

    // ---- A fragments via ds_read_b128, named regs: A[m=lrow][k=quad*8+j] ----
    half8 AH00, AH01, AH10, AH11, AH20, AH21, AH30, AH31;
#define LOADA(rt)                                                              \
    AH##rt##0 = *(const half8*)&XsH[(rt * 16 + lrow) * XH_STR + quad * 8];     \
    AH##rt##1 = *(const half8*)&XsH[(rt * 16 + lrow) * XH_STR + 32 + quad * 8];
    LOADA(0) LOADA(1) LOADA(2) LOADA(3)
#undef LOADA

    float m1[4][4], m2[4][4];
#pragma unroll
    for (int rt = 0; rt < 4; ++rt)
#pragma unroll
        for (int i = 0; i < 4; ++i) {
            m1[rt][i] = __uint_as_float(0x7F800000u);   // +inf (low 9 bits 0)
            m2[rt][i] = __uint_as_float(0x7F800000u);
        }

    // ---- main loop: 8 code-tiles, depth-4 NAMED-reg prefetch ----
#pragma unroll 1
    for (int nt = 0; nt < 8; nt += 4) {
        PROCESS4(nt, fa0, fa1, esa)
        int n4 = (nt + 4 < 8) ? nt + 4 : 7;   // clamped harmless reload
        LOADB(n4, fa0, fa1, esa)
        PROCESS4(nt + 1, fb0, fb1, esb)
        int n5 = (nt + 5 < 8) ? nt + 5 : 7;
        LOADB(n5, fb0, fb1, esb)
        PROCESS4(nt + 2, fc0, fc1, esc)
        int n6 = (nt + 6 < 8) ? nt + 6 : 7;
        LOADB(n6, fc0, fc1, esc)
        PROCESS4(nt + 3, fd0, fd1, esd)
        int n7 = (nt + 7 < 8) ? nt + 7 : 7;
        LOADB(n7, fd0, fd1, esd)
    }

    // ---- wave-local row-min over the 16 n-lanes (per rt,i) ----
    float g1[4][4];
#pragma unroll
    for (int rt = 0; rt < 4; ++rt)
#pragma unroll
        for (int i = 0; i < 4; ++i) g1[rt][i] = m1[rt][i];
#pragma unroll
    for (int s = 1; s <= 8; s <<= 1)
#pragma unroll
        for (int rt = 0; rt < 4; ++rt)
#pragma unroll
            for (int i = 0; i < 4; ++i)
                g1[rt][i] = fminf(g1[rt][i], __shfl_xor(g1[rt][i], s));

    // ---- push candidates: winner -> fixed slot m (keys unique, exactly one
    //      lane matches g1); near-tie extras -> atomic slots 64+ ----
#pragma unroll
    for (int rt = 0; rt < 4; ++rt)
#pragma unroll
        for (int i = 0; i < 4; ++i) {
            int m = rt * 16 + quad * 4 + i;            // block-local row 0..63
            float thr = clr9(g1[rt][i]) + EPS;
            if (m1[rt][i] == g1[rt][i]) {
                qbuf[wave * QW + m] = (unsigned short)
                    (((unsigned)m << 9) | (__float_as_uint(m1[rt][i]) & 511u));
            } else if (clr9(m1[rt][i]) <= thr) {
                int id = atomicAdd(&qcnt[wave], 1);
                if (id < QW)
                    qbuf[wave * QW + id] = (unsigned short)
                        (((unsigned)m << 9) | (__float_as_uint(m1[rt][i]) & 511u));
            }
            if (clr9(m2[rt][i]) <= thr) {
                int id = atomicAdd(&qcnt[wave], 1);
                if (id < QW)
                    qbuf[wave * QW + id] = (unsigned short)
                        (((unsigned)m << 9) | (__float_as_uint(m2[rt][i]) & 511u));
            }
        }
    asm volatile("s_waitcnt lgkmcnt(0)");   // wave-local queue visible

    // ---- exact fp32 recheck (same fmaf order as R1 kernel), wave-local ----
    int qc = atomicAdd(&qcnt[wave], 0);
    if (qc > QW) qc = QW;
    for (int qi = lane; qi < qc; qi += 64) {
        unsigned e = qbuf[wave * QW + qi];
        int m = (int)(e >> 9), n = (int)(e & 511u);
        const float4* er = (const float4*)(embed + n * VQ_D);
        const float* xr = &Xs32[m * X32_STR];
        float dot = 0.f;
#pragma unroll
        for (int d4 = 0; d4 < 16; ++d4) {
            float4 ev = er[d4];
            dot = fmaf(xr[4 * d4 + 0], ev.x, dot);
            dot = fmaf(xr[4 * d4 + 1], ev.y, dot);
            dot = fmaf(xr[4 * d4 + 2], ev.z, dot);
            dot = fmaf(xr[4 * d4 + 3], ev.w, dot);
        }
        float v = fmaf(-2.f, dot, esq[n]);
        unsigned long long key =
            (((unsigned long long)fenc(v)) << 32) | (unsigned)n;
        atomicMin(&row_best[m], key);   // exact order; equal dist -> smaller n
    }
    __syncthreads();   // barrier 2: all waves' rechecks done

    // ---- outputs: indices + fully-coalesced quantized rows ----
    if (t < ROWS) out_idx[n0 + t] = (float)(unsigned)(row_best[t] & 0xffffffffu);

#pragma unroll
    for (int it = 0; it < 4; ++it) {
        int o   = it * 1024 + t * 4;          // 64 rows x 64 floats, contiguous
        int row = o >> 6;
        int col = o & 63;
        unsigned k = (unsigned)(row_best[row] & 0xffffffffu);
        float4 val = *(const float4*)(embed + k * VQ_D + col);
        *(float4*)(out_q + (size_t)n0 * VQ_D + o) = val;
    }
}

extern "C" void kernel_launch(void* const* d_in, const int* in_sizes, int n_in,
                              void* d_out, int out_size, void* d_ws, size_t ws_size,
                              hipStream_t stream) {
    const float* x     = (const float*)d_in[0];
    const float* embed = (const float*)d_in[1];
    float* out_q   = (float*)d_out;
    float* out_idx = (float*)d_out + (size_t)VQ_N * VQ_D;

    float* esq    = (float*)d_ws;                           // 512 f
    _Float16* EH  = (_Float16*)((char*)d_ws + 2048);        // 512*64 f16

    vq_prep_kernel<<<(VQ_K * VQ_D) / 256, 256, 0, stream>>>(embed, EH, esq);
    vq_mfma_kernel<<<VQ_N / ROWS, 256, 0, stream>>>(x, embed, esq, EH, out_q, out_idx);
}